// Round 19
// baseline (42.693 us; speedup 1.0000x reference)
//
#include <hip/hip_runtime.h>
#include <hip/hip_bf16.h>
#include <hip/hip_fp16.h>

#define BB 8
#define NN 1024
#define FIN 128
#define FOUT 64
#define HH 4
#define EPSV 1e-7f
#define SLOPE 0.2f
#define LOG2E 1.44269504088896340736f

typedef _Float16 v8h __attribute__((ext_vector_type(8)));
typedef _Float16 v4h __attribute__((ext_vector_type(4)));
typedef _Float16 v2h __attribute__((ext_vector_type(2)));
typedef __fp16 v2hf __attribute__((ext_vector_type(2)));
typedef float v4f __attribute__((ext_vector_type(4)));

union U8 { v2h p[4]; v8h v; };
union U2 { v2hf hf; v2h h; };

__device__ __forceinline__ v2h clamp01(v2h x) {
  v2h zero = {(_Float16)0.0f, (_Float16)0.0f};
  v2h one = {(_Float16)1.0f, (_Float16)1.0f};
  return __builtin_elementwise_min(__builtin_elementwise_max(x, zero), one);
}

__device__ __forceinline__ v2h cvt2(float a, float b) {
  U2 u;
  u.hf = __builtin_amdgcn_cvt_pkrtz(a, b);
  return u.h;
}

__device__ __forceinline__ float dot2(v2h a, v2h b, float c) {
  U2 ua, ub;
  ua.h = a;
  ub.h = b;
  return __builtin_amdgcn_fdot2(ua.hf, ub.hf, c, false);
}

// ---- K1 (k0 fused): per-block W->LDS tiled transpose; Wh = x@W MFMA;
//      s_i/s_j + exp tables; Wh stored TILED; zeroes colsum. grid 512. ------
__global__ __launch_bounds__(256) void k1_whm(
    const float* __restrict__ x, const float* __restrict__ W,
    const float* __restrict__ aw, const float* __restrict__ ab,
    _Float16* __restrict__ WhTt, float* __restrict__ si2,
    _Float16* __restrict__ tjh, _Float16* __restrict__ djh,
    _Float16* __restrict__ e2jh, float* __restrict__ e2i_t,
    float* __restrict__ di_t, float* __restrict__ colsum) {
  __shared__ _Float16 wlds[32768];  // [ct][kgg][ln][e] tiled W (64 KB)
  __shared__ _Float16 xs[16][136];
  int tid = threadIdx.x;
  int bid = blockIdx.x;
  if (tid < 64) colsum[bid * 64 + tid] = 0.0f;  // 512*64 = B*H*N
  // stage W -> LDS in tiled f16 layout (coalesced float4 reads)
#pragma unroll 4
  for (int it = 0; it < 32; ++it) {
    int idx4 = it * 256 + tid;          // 8192 float4 = 32768 floats
    int base = idx4 * 4;
    int h = base >> 13, k = (base >> 6) & 127, o0 = base & 63;
    float4 v = *(const float4*)(W + (size_t)h * 8192 + k * 64 + o0);
    int kgg = k >> 3, e = k & 7;
#pragma unroll
    for (int q = 0; q < 4; ++q) {
      int c = h * 64 + o0 + q;
      int ct = c >> 4, ln = c & 15;
      float val = (q == 0) ? v.x : (q == 1) ? v.y : (q == 2) ? v.z : v.w;
      wlds[(((ct * 16) + kgg) * 16 + ln) * 8 + e] = (_Float16)val;
    }
  }
  // stage x tile
#pragma unroll
  for (int t2 = 0; t2 < 2; ++t2) {
    int idx = t2 * 256 + tid;
    int row = idx >> 5, c4 = (idx & 31) * 4;
    float4 v = *(const float4*)(x + ((size_t)bid * 16 + row) * FIN + c4);
    v4h hv;
    hv[0] = (_Float16)v.x; hv[1] = (_Float16)v.y;
    hv[2] = (_Float16)v.z; hv[3] = (_Float16)v.w;
    *(v4h*)(&xs[row][c4]) = hv;
  }
  __syncthreads();
  int w = tid >> 6, l = tid & 63;
  int kg = l >> 4, ln = l & 15;
  v4f acc[4] = {{}, {}, {}, {}};
#pragma unroll
  for (int ks = 0; ks < 4; ++ks) {
    v8h af = *(const v8h*)(&xs[ln][ks * 32 + kg * 8]);
    int kgg = ks * 4 + kg;
#pragma unroll
    for (int t = 0; t < 4; ++t) {
      int ct = w * 4 + t;
      v8h bf = *(const v8h*)(&wlds[(((ct * 16) + kgg) * 16 + ln) * 8]);
      acc[t] = __builtin_amdgcn_mfma_f32_16x16x32_f16(af, bf, acc[t], 0, 0, 0);
    }
  }
  float a1v[4], a2v[4];
#pragma unroll
  for (int t = 0; t < 4; ++t) {
    a1v[t] = aw[w * 128 + t * 16 + ln];
    a2v[t] = aw[w * 128 + 64 + t * 16 + ln];
  }
  float abv = ab[w];
#pragma unroll
  for (int r = 0; r < 4; ++r) {
    float v1 = acc[0][r] * a1v[0] + acc[1][r] * a1v[1] +
               acc[2][r] * a1v[2] + acc[3][r] * a1v[3];
    float v2 = acc[0][r] * a2v[0] + acc[1][r] * a2v[1] +
               acc[2][r] * a2v[2] + acc[3][r] * a2v[3];
#pragma unroll
    for (int off = 1; off < 16; off <<= 1) {
      v1 += __shfl_xor(v1, off);
      v2 += __shfl_xor(v2, off);
    }
    if (ln == 0) {
      int gr = bid * 16 + kg * 4 + r;
      int b_ = gr >> 10, n_ = gr & 1023;
      size_t row = ((size_t)b_ * HH + w) * NN + n_;
      float v1L = v1 * LOG2E;
      float tjL = (v2 + abv) * LOG2E;
      si2[row] = v1L;
      float e1i = __builtin_amdgcn_exp2f(v1L);
      float e2i = __builtin_amdgcn_exp2f(0.2f * v1L);
      e2i_t[row] = e2i;
      di_t[row] = e1i - e2i;
      float e1j = __builtin_amdgcn_exp2f(tjL);
      float e2j = __builtin_amdgcn_exp2f(0.2f * tjL);
      tjh[row] = (_Float16)tjL;
      e2jh[row] = (_Float16)e2j;
      djh[row] = (_Float16)(e1j - e2j);
    }
  }
  // tiled store: WhTt[((bh*32+jb)*64+o)*32+jj]
  {
    int b_ = bid >> 6;
    int bh = b_ * HH + w;
    int jb = (bid & 63) >> 1;
    int jj0 = (bid & 1) * 16 + kg * 4;
#pragma unroll
    for (int t = 0; t < 4; ++t) {
      v4h hv;
#pragma unroll
      for (int r = 0; r < 4; ++r) hv[r] = (_Float16)acc[t][r];
      *(v4h*)(WhTt + (((size_t)bh * 32 + jb) * 64 + (t * 16 + ln)) * 32 +
              jj0) = hv;
    }
  }
}

// ------- KB: column sums via packed-f16 interp P + fdot2 + A bit-pack;
//         sums accumulated into colsum via atomicAdd. -----------------------
__global__ __launch_bounds__(256) void kb_colsum_bits(
    const float* __restrict__ A, const float* __restrict__ si2,
    const float* __restrict__ e2i_t, const float* __restrict__ di_t,
    const _Float16* __restrict__ tjh, const _Float16* __restrict__ djh,
    const _Float16* __restrict__ e2jh, float* __restrict__ colsum,
    unsigned long long* __restrict__ Abits) {
  __shared__ v2h si_p[4][16], di_p[4][16], e2i_p[4][16];
  int b = blockIdx.z, is = blockIdx.y, jt = blockIdx.x;
  int tid = threadIdx.x;
  int w = tid >> 6, lane = tid & 63;
  int j = jt * 256 + tid;
  int i0 = is * 32;
  if (tid < 64) {
    int h = tid >> 4, pp = tid & 15;
    size_t row = ((size_t)(b * HH + h)) * NN + i0 + 2 * pp;
    si_p[h][pp] = cvt2(si2[row], si2[row + 1]);
    di_p[h][pp] = cvt2(di_t[row], di_t[row + 1]);
    e2i_p[h][pp] = cvt2(e2i_t[row], e2i_t[row + 1]);
  }
  __syncthreads();
  v2h tjb[4], djb[4], ejb[4];
#pragma unroll
  for (int h = 0; h < 4; ++h) {
    size_t jr = ((size_t)(b * HH + h)) * NN + j;
    _Float16 t = tjh[jr], d = djh[jr], e = e2jh[jr];
    tjb[h][0] = t; tjb[h][1] = t;
    djb[h][0] = d; djb[h][1] = d;
    ejb[h][0] = e; ejb[h][1] = e;
  }
  v2h big = {(_Float16)4096.0f, (_Float16)4096.0f};
  float acc[4] = {0.f, 0.f, 0.f, 0.f};
  const float* Ap = A + ((size_t)b * NN + i0) * NN + j;
  unsigned long long myword = 0ull;
#pragma unroll
  for (int c = 0; c < 4; ++c) {
    float av[8];
#pragma unroll
    for (int q = 0; q < 8; ++q) av[q] = Ap[(size_t)(c * 8 + q) * NN];
    v2h apk[4];
#pragma unroll
    for (int q = 0; q < 4; ++q) apk[q] = cvt2(av[2 * q], av[2 * q + 1]);
#pragma unroll
    for (int q = 0; q < 8; ++q) {
      unsigned long long m = __ballot(av[q] != 0.0f);
      if (lane == c * 8 + q) myword = m;
    }
#pragma unroll
    for (int h = 0; h < 4; ++h) {
      U8 si4, di4, ei4;
      si4.v = *(const v8h*)&si_p[h][c * 4];
      di4.v = *(const v8h*)&di_p[h][c * 4];
      ei4.v = *(const v8h*)&e2i_p[h][c * 4];
#pragma unroll
      for (int pp = 0; pp < 4; ++pp) {
        v2h f = si4.p[pp] + tjb[h];
        v2h s = clamp01(f * big);
        v2h ei = s * di4.p[pp] + ei4.p[pp];
        v2h ej = s * djb[h] + ejb[h];
        v2h p = ei * ej;
        acc[h] = dot2(p, apk[pp], acc[h]);
      }
    }
  }
  if (lane < 32)
    Abits[((size_t)b * NN + i0 + lane) * 16 + jt * 4 + w] = myword;
#pragma unroll
  for (int h = 0; h < 4; ++h)
    atomicAdd(&colsum[((size_t)(b * HH + h)) * NN + j], acc[h]);
}

// ---------------- K4: out = P' @ Wh via MFMA, 64-row i-tiles ----------------
__global__ __launch_bounds__(512, 4) void k4_pv(
    const unsigned long long* __restrict__ Abits,
    const float* __restrict__ si2, const _Float16* __restrict__ tjh,
    const _Float16* __restrict__ djh, const _Float16* __restrict__ e2jh,
    const float* __restrict__ e2i_t, const float* __restrict__ di_t,
    const _Float16* __restrict__ WhTt, const float* __restrict__ colsum,
    float* __restrict__ out) {
  __shared__ unsigned long long Ab[64][17];
  __shared__ _Float16 tjl[2][1024];
  __shared__ _Float16 djl[2][1024];
  __shared__ _Float16 e2jl[2][1024];
  __shared__ _Float16 lut[256][8];
  __shared__ float sil[2][64], e2il[2][64], dil[2][64];
  __shared__ float red[2][2][64][33];
  int bid = blockIdx.x;
  int b = bid & 7, hp = (bid >> 3) & 1, it = bid >> 4;
  int i0 = it * 64;
  int tid = threadIdx.x;
  {
    size_t base = (size_t)(b * HH + hp * 2) * NN;
#pragma unroll
    for (int t2 = 0; t2 < 4; ++t2) {
      int idx = t2 * 512 + tid;
      int hh = idx >> 10, j = idx & 1023;
      size_t row = base + (size_t)hh * NN + j;
      float rr = 1.0f / (colsum[row] + EPSV);
      tjl[hh][j] = tjh[row];
      djl[hh][j] = (_Float16)((float)djh[row] * rr);
      e2jl[hh][j] = (_Float16)((float)e2jh[row] * rr);
    }
  }
  if (tid < 128) {
    int hh = tid >> 6, ii = tid & 63;
    size_t row = (size_t)(b * HH + hp * 2 + hh) * NN + i0 + ii;
    sil[hh][ii] = si2[row];
    e2il[hh][ii] = e2i_t[row];
    dil[hh][ii] = di_t[row];
  }
  if (tid < 256) {
#pragma unroll
    for (int e = 0; e < 8; ++e)
      lut[tid][e] = ((tid >> e) & 1) ? (_Float16)1.0f : (_Float16)0.0f;
  }
  {
#pragma unroll
    for (int t2 = 0; t2 < 2; ++t2) {
      int idx = t2 * 512 + tid;
      int row = idx >> 4, word = idx & 15;
      Ab[row][word] = Abits[((size_t)b * NN + i0 + row) * 16 + word];
    }
  }
  __syncthreads();

  int w = tid >> 6, l = tid & 63;
  int hh = w & 1, jq4 = w >> 1;
  int kg = l >> 4, ln = l & 15;
  v2h si_f[4], e2_f[4], di_f[4];
#pragma unroll
  for (int f = 0; f < 4; ++f) {
    _Float16 s = (_Float16)sil[hh][f * 16 + ln];
    _Float16 e = (_Float16)e2il[hh][f * 16 + ln];
    _Float16 d = (_Float16)dil[hh][f * 16 + ln];
    si_f[f][0] = s; si_f[f][1] = s;
    e2_f[f][0] = e; e2_f[f][1] = e;
    di_f[f][0] = d; di_f[f][1] = d;
  }
  v2h big = {(_Float16)4096.0f, (_Float16)4096.0f};
  int bh = b * HH + hp * 2 + hh;
  v4f acc[4][4] = {};
  const _Float16* VTb = WhTt + (size_t)bh * 32 * 64 * 32;
  int jbase = jq4 * 256;

  for (int jq = 0; jq < 8; ++jq) {
    int j = jbase + jq * 32 + kg * 8;
    int widx = j >> 6, sh = j & 63;
    U8 tj8, dj8, ej8;
    tj8.v = *(const v8h*)&tjl[hh][j];
    dj8.v = *(const v8h*)&djl[hh][j];
    ej8.v = *(const v8h*)&e2jl[hh][j];
    const _Float16* vb = VTb + (size_t)(j >> 5) * 2048 + kg * 8;
    v8h b0 = *(const v8h*)(vb + (0 * 16 + ln) * 32);
    v8h b1 = *(const v8h*)(vb + (1 * 16 + ln) * 32);
    v8h b2 = *(const v8h*)(vb + (2 * 16 + ln) * 32);
    v8h b3 = *(const v8h*)(vb + (3 * 16 + ln) * 32);
#pragma unroll
    for (int f = 0; f < 4; ++f) {
      unsigned int bits = (unsigned int)(Ab[f * 16 + ln][widx] >> sh) & 0xffu;
      U8 m, af;
      m.v = *(const v8h*)&lut[bits][0];
#pragma unroll
      for (int q = 0; q < 4; ++q) {
        v2h fv = tj8.p[q] + si_f[f];
        v2h s = clamp01(fv * big);
        v2h ej = s * dj8.p[q] + ej8.p[q];
        v2h ei = s * di_f[f] + e2_f[f];
        af.p[q] = ei * ej * m.p[q];
      }
      acc[f][0] =
          __builtin_amdgcn_mfma_f32_16x16x32_f16(af.v, b0, acc[f][0], 0, 0, 0);
      acc[f][1] =
          __builtin_amdgcn_mfma_f32_16x16x32_f16(af.v, b1, acc[f][1], 0, 0, 0);
      acc[f][2] =
          __builtin_amdgcn_mfma_f32_16x16x32_f16(af.v, b2, acc[f][2], 0, 0, 0);
      acc[f][3] =
          __builtin_amdgcn_mfma_f32_16x16x32_f16(af.v, b3, acc[f][3], 0, 0, 0);
    }
  }

#pragma unroll
  for (int pass = 0; pass < 2; ++pass) {
    int fA = pass * 2, fB = pass * 2 + 1;
    if (pass) __syncthreads();
    if (jq4 == 1 || jq4 == 3) {
      int slot = jq4 >> 1;
#pragma unroll
      for (int t = 0; t < 4; ++t)
#pragma unroll
        for (int r = 0; r < 4; ++r) {
          red[hh][slot][l][t * 4 + r] = acc[fA][t][r];
          red[hh][slot][l][16 + t * 4 + r] = acc[fB][t][r];
        }
    }
    __syncthreads();
    if (jq4 == 0 || jq4 == 2) {
      int slot = jq4 >> 1;
#pragma unroll
      for (int t = 0; t < 4; ++t)
#pragma unroll
        for (int r = 0; r < 4; ++r) {
          acc[fA][t][r] += red[hh][slot][l][t * 4 + r];
          acc[fB][t][r] += red[hh][slot][l][16 + t * 4 + r];
        }
    }
    __syncthreads();
    if (jq4 == 2) {
#pragma unroll
      for (int t = 0; t < 4; ++t)
#pragma unroll
        for (int r = 0; r < 4; ++r) {
          red[hh][0][l][t * 4 + r] = acc[fA][t][r];
          red[hh][0][l][16 + t * 4 + r] = acc[fB][t][r];
        }
    }
    __syncthreads();
    if (jq4 == 0) {
#pragma unroll
      for (int t = 0; t < 4; ++t)
#pragma unroll
        for (int r = 0; r < 4; ++r) {
          acc[fA][t][r] += red[hh][0][l][t * 4 + r];
          acc[fB][t][r] += red[hh][0][l][16 + t * 4 + r];
        }
#pragma unroll
      for (int r = 0; r < 4; ++r) {
        int giA = i0 + fA * 16 + kg * 4 + r;
        float* opA = out + ((size_t)b * NN + giA) * 256 + (hp * 2 + hh) * 64;
        opA[0 * 16 + ln] = acc[fA][0][r];
        opA[1 * 16 + ln] = acc[fA][1][r];
        opA[2 * 16 + ln] = acc[fA][2][r];
        opA[3 * 16 + ln] = acc[fA][3][r];
        float* opB = opA + 16 * 256;
        opB[0 * 16 + ln] = acc[fB][0][r];
        opB[1 * 16 + ln] = acc[fB][1][r];
        opB[2 * 16 + ln] = acc[fB][2][r];
        opB[3 * 16 + ln] = acc[fB][3][r];
      }
    }
  }
}

extern "C" void kernel_launch(void* const* d_in, const int* in_sizes, int n_in,
                              void* d_out, int out_size, void* d_ws,
                              size_t ws_size, hipStream_t stream) {
  const float* A = (const float*)d_in[0];
  const float* x = (const float*)d_in[1];
  const float* W = (const float*)d_in[2];
  const float* aw = (const float*)d_in[3];
  const float* ab = (const float*)d_in[4];
  float* out = (float*)d_out;
  char* ws = (char*)d_ws;
  _Float16* WhTt = (_Float16*)ws;                       // 4 MB tiled Wh
  float* si2 = (float*)(ws + (4u << 20));                   // 128 KB
  float* colsum = (float*)(ws + (4u << 20) + (128u << 10)); // 128 KB
  unsigned long long* Abits =
      (unsigned long long*)(ws + (4u << 20) + (256u << 10));  // 1 MB
  char* tb = ws + (5u << 20) + (256u << 10);
  _Float16* tjh = (_Float16*)tb;                   // 64 KB (B,H,N) f16
  _Float16* djh = (_Float16*)(tb + (64u << 10));   // 64 KB
  _Float16* e2jh = (_Float16*)(tb + (128u << 10)); // 64 KB
  float* e2i_t = (float*)(tb + (192u << 10));      // 128 KB
  float* di_t = (float*)(tb + (320u << 10));       // 128 KB

  hipLaunchKernelGGL(k1_whm, dim3(512), dim3(256), 0, stream, x, W, aw, ab,
                     WhTt, si2, tjh, djh, e2jh, e2i_t, di_t, colsum);
  hipLaunchKernelGGL(kb_colsum_bits, dim3(4, 32, BB), dim3(256), 0, stream, A,
                     si2, e2i_t, di_t, tjh, djh, e2jh, colsum, Abits);
  hipLaunchKernelGGL(k4_pv, dim3(256), dim3(512), 0, stream, Abits, si2, tjh,
                     djh, e2jh, e2i_t, di_t, WhTt, colsum, out);
}

// Round 20
// 41.363 us; speedup vs baseline: 1.0322x; 1.0322x over previous
//
#include <hip/hip_runtime.h>
#include <hip/hip_bf16.h>
#include <hip/hip_fp16.h>

#define BB 8
#define NN 1024
#define FIN 128
#define FOUT 64
#define HH 4
#define EPSV 1e-7f
#define SLOPE 0.2f
#define LOG2E 1.44269504088896340736f

typedef _Float16 v8h __attribute__((ext_vector_type(8)));
typedef _Float16 v4h __attribute__((ext_vector_type(4)));
typedef _Float16 v2h __attribute__((ext_vector_type(2)));
typedef __fp16 v2hf __attribute__((ext_vector_type(2)));
typedef float v4f __attribute__((ext_vector_type(4)));

union U8 { v2h p[4]; v8h v; };
union U2 { v2hf hf; v2h h; };

__device__ __forceinline__ v2h clamp01(v2h x) {
  v2h zero = {(_Float16)0.0f, (_Float16)0.0f};
  v2h one = {(_Float16)1.0f, (_Float16)1.0f};
  return __builtin_elementwise_min(__builtin_elementwise_max(x, zero), one);
}

__device__ __forceinline__ v2h cvt2(float a, float b) {
  U2 u;
  u.hf = __builtin_amdgcn_cvt_pkrtz(a, b);
  return u.h;
}

__device__ __forceinline__ float dot2(v2h a, v2h b, float c) {
  U2 ua, ub;
  ua.h = a;
  ub.h = b;
  return __builtin_amdgcn_fdot2(ua.hf, ub.hf, c, false);
}

// ---------------- K0: Wtt[ct][kgg][16][8] ----------------
__global__ __launch_bounds__(256) void k0_wt(const float* __restrict__ W,
                                             _Float16* __restrict__ Wtt) {
  for (int it = 0; it < 16; ++it) {
    int idx = blockIdx.x * 4096 + it * 256 + threadIdx.x;
    int e = idx & 7, ln = (idx >> 3) & 15, kgg = (idx >> 7) & 15,
        ct = idx >> 11;
    int c = ct * 16 + ln, k = kgg * 8 + e;
    Wtt[idx] = (_Float16)W[(size_t)(c >> 6) * 8192 + k * 64 + (c & 63)];
  }
}

// ---- K1: Wh = x@W MFMA; s_i/s_j + exp tables; Wh stored TILED (unscaled);
//      also zeroes colsum (for kb's atomics). grid 512, block 256. ----------
__global__ __launch_bounds__(256) void k1_whm(
    const float* __restrict__ x, const _Float16* __restrict__ Wtt,
    const float* __restrict__ aw, const float* __restrict__ ab,
    _Float16* __restrict__ WhTt, float* __restrict__ si2,
    _Float16* __restrict__ tjh, _Float16* __restrict__ djh,
    _Float16* __restrict__ e2jh, float* __restrict__ e2i_t,
    float* __restrict__ di_t, float* __restrict__ colsum) {
  __shared__ _Float16 xs[16][136];
  int tid = threadIdx.x;
  int bid = blockIdx.x;
  if (tid < 64) colsum[bid * 64 + tid] = 0.0f;  // 512*64 = 32768 = B*H*N
#pragma unroll
  for (int t2 = 0; t2 < 2; ++t2) {
    int idx = t2 * 256 + tid;
    int row = idx >> 5, c4 = (idx & 31) * 4;
    float4 v = *(const float4*)(x + ((size_t)bid * 16 + row) * FIN + c4);
    v4h hv;
    hv[0] = (_Float16)v.x; hv[1] = (_Float16)v.y;
    hv[2] = (_Float16)v.z; hv[3] = (_Float16)v.w;
    *(v4h*)(&xs[row][c4]) = hv;
  }
  __syncthreads();
  int w = tid >> 6, l = tid & 63;
  int kg = l >> 4, ln = l & 15;
  v4f acc[4] = {{}, {}, {}, {}};
#pragma unroll
  for (int ks = 0; ks < 4; ++ks) {
    v8h af = *(const v8h*)(&xs[ln][ks * 32 + kg * 8]);
    int kgg = ks * 4 + kg;
#pragma unroll
    for (int t = 0; t < 4; ++t) {
      int ct = w * 4 + t;
      v8h bf = *(const v8h*)(Wtt + (((size_t)ct * 16 + kgg) * 16 + ln) * 8);
      acc[t] = __builtin_amdgcn_mfma_f32_16x16x32_f16(af, bf, acc[t], 0, 0, 0);
    }
  }
  float a1v[4], a2v[4];
#pragma unroll
  for (int t = 0; t < 4; ++t) {
    a1v[t] = aw[w * 128 + t * 16 + ln];
    a2v[t] = aw[w * 128 + 64 + t * 16 + ln];
  }
  float abv = ab[w];
#pragma unroll
  for (int r = 0; r < 4; ++r) {
    float v1 = acc[0][r] * a1v[0] + acc[1][r] * a1v[1] +
               acc[2][r] * a1v[2] + acc[3][r] * a1v[3];
    float v2 = acc[0][r] * a2v[0] + acc[1][r] * a2v[1] +
               acc[2][r] * a2v[2] + acc[3][r] * a2v[3];
#pragma unroll
    for (int off = 1; off < 16; off <<= 1) {
      v1 += __shfl_xor(v1, off);
      v2 += __shfl_xor(v2, off);
    }
    if (ln == 0) {
      int gr = bid * 16 + kg * 4 + r;
      int b_ = gr >> 10, n_ = gr & 1023;
      size_t row = ((size_t)b_ * HH + w) * NN + n_;
      float v1L = v1 * LOG2E;
      float tjL = (v2 + abv) * LOG2E;
      si2[row] = v1L;
      float e1i = __builtin_amdgcn_exp2f(v1L);
      float e2i = __builtin_amdgcn_exp2f(0.2f * v1L);
      e2i_t[row] = e2i;
      di_t[row] = e1i - e2i;
      float e1j = __builtin_amdgcn_exp2f(tjL);
      float e2j = __builtin_amdgcn_exp2f(0.2f * tjL);
      tjh[row] = (_Float16)tjL;
      e2jh[row] = (_Float16)e2j;
      djh[row] = (_Float16)(e1j - e2j);
    }
  }
  // tiled store: WhTt[((bh*32 + jb)*64 + o)*32 + jj], o = t*16+ln,
  // jb = (bid&63)>>1, jj = (bid&1)*16 + kg*4 + r (4 consecutive -> v4h)
  {
    int b_ = bid >> 6;
    int bh = b_ * HH + w;
    int jb = (bid & 63) >> 1;
    int jj0 = (bid & 1) * 16 + kg * 4;
#pragma unroll
    for (int t = 0; t < 4; ++t) {
      v4h hv;
#pragma unroll
      for (int r = 0; r < 4; ++r) hv[r] = (_Float16)acc[t][r];
      *(v4h*)(WhTt + (((size_t)bh * 32 + jb) * 64 + (t * 16 + ln)) * 32 +
              jj0) = hv;
    }
  }
}

// ------- KB: column sums via packed-f16 interp P + fdot2 + A bit-pack;
//         sums accumulated into colsum via atomicAdd (k3 eliminated). -------
__global__ __launch_bounds__(256) void kb_colsum_bits(
    const float* __restrict__ A, const float* __restrict__ si2,
    const float* __restrict__ e2i_t, const float* __restrict__ di_t,
    const _Float16* __restrict__ tjh, const _Float16* __restrict__ djh,
    const _Float16* __restrict__ e2jh, float* __restrict__ colsum,
    unsigned long long* __restrict__ Abits) {
  __shared__ v2h si_p[4][16], di_p[4][16], e2i_p[4][16];
  int b = blockIdx.z, is = blockIdx.y, jt = blockIdx.x;
  int tid = threadIdx.x;
  int w = tid >> 6, lane = tid & 63;
  int j = jt * 256 + tid;
  int i0 = is * 32;
  if (tid < 64) {
    int h = tid >> 4, pp = tid & 15;
    size_t row = ((size_t)(b * HH + h)) * NN + i0 + 2 * pp;
    si_p[h][pp] = cvt2(si2[row], si2[row + 1]);
    di_p[h][pp] = cvt2(di_t[row], di_t[row + 1]);
    e2i_p[h][pp] = cvt2(e2i_t[row], e2i_t[row + 1]);
  }
  __syncthreads();
  v2h tjb[4], djb[4], ejb[4];
#pragma unroll
  for (int h = 0; h < 4; ++h) {
    size_t jr = ((size_t)(b * HH + h)) * NN + j;
    _Float16 t = tjh[jr], d = djh[jr], e = e2jh[jr];
    tjb[h][0] = t; tjb[h][1] = t;
    djb[h][0] = d; djb[h][1] = d;
    ejb[h][0] = e; ejb[h][1] = e;
  }
  v2h big = {(_Float16)4096.0f, (_Float16)4096.0f};
  float acc[4] = {0.f, 0.f, 0.f, 0.f};
  const float* Ap = A + ((size_t)b * NN + i0) * NN + j;
  unsigned long long myword = 0ull;
#pragma unroll
  for (int c = 0; c < 4; ++c) {
    float av[8];
#pragma unroll
    for (int q = 0; q < 8; ++q) av[q] = Ap[(size_t)(c * 8 + q) * NN];
    v2h apk[4];
#pragma unroll
    for (int q = 0; q < 4; ++q) apk[q] = cvt2(av[2 * q], av[2 * q + 1]);
#pragma unroll
    for (int q = 0; q < 8; ++q) {
      unsigned long long m = __ballot(av[q] != 0.0f);
      if (lane == c * 8 + q) myword = m;
    }
#pragma unroll
    for (int h = 0; h < 4; ++h) {
      U8 si4, di4, ei4;
      si4.v = *(const v8h*)&si_p[h][c * 4];
      di4.v = *(const v8h*)&di_p[h][c * 4];
      ei4.v = *(const v8h*)&e2i_p[h][c * 4];
#pragma unroll
      for (int pp = 0; pp < 4; ++pp) {
        v2h f = si4.p[pp] + tjb[h];
        v2h s = clamp01(f * big);
        v2h ei = s * di4.p[pp] + ei4.p[pp];
        v2h ej = s * djb[h] + ejb[h];
        v2h p = ei * ej;
        acc[h] = dot2(p, apk[pp], acc[h]);
      }
    }
  }
  if (lane < 32)
    Abits[((size_t)b * NN + i0 + lane) * 16 + jt * 4 + w] = myword;
#pragma unroll
  for (int h = 0; h < 4; ++h)
    atomicAdd(&colsum[((size_t)(b * HH + h)) * NN + j], acc[h]);
}

// ---------------- K4: out = P' @ Wh via MFMA, 64-row i-tiles ----------------
// r[j] = 1/(colsum+eps) folded into dj/e2j tables AT STAGING (hot loop
// unchanged); V' = unscaled tiled Wh. grid 256, block 512.
__global__ __launch_bounds__(512, 4) void k4_pv(
    const unsigned long long* __restrict__ Abits,
    const float* __restrict__ si2, const _Float16* __restrict__ tjh,
    const _Float16* __restrict__ djh, const _Float16* __restrict__ e2jh,
    const float* __restrict__ e2i_t, const float* __restrict__ di_t,
    const _Float16* __restrict__ WhTt, const float* __restrict__ colsum,
    float* __restrict__ out) {
  __shared__ unsigned long long Ab[64][17];
  __shared__ _Float16 tjl[2][1024];
  __shared__ _Float16 djl[2][1024];
  __shared__ _Float16 e2jl[2][1024];
  __shared__ _Float16 lut[256][8];
  __shared__ float sil[2][64], e2il[2][64], dil[2][64];
  __shared__ float red[2][2][64][33];
  int bid = blockIdx.x;
  int b = bid & 7, hp = (bid >> 3) & 1, it = bid >> 4;
  int i0 = it * 64;
  int tid = threadIdx.x;
  // stage j-tables with r[j] folded into dj/e2j
  {
    size_t base = (size_t)(b * HH + hp * 2) * NN;
#pragma unroll
    for (int t2 = 0; t2 < 4; ++t2) {
      int idx = t2 * 512 + tid;
      int hh = idx >> 10, j = idx & 1023;
      size_t row = base + (size_t)hh * NN + j;
      float rr = 1.0f / (colsum[row] + EPSV);
      tjl[hh][j] = tjh[row];
      djl[hh][j] = (_Float16)((float)djh[row] * rr);
      e2jl[hh][j] = (_Float16)((float)e2jh[row] * rr);
    }
  }
  if (tid < 128) {
    int hh = tid >> 6, ii = tid & 63;
    size_t row = (size_t)(b * HH + hp * 2 + hh) * NN + i0 + ii;
    sil[hh][ii] = si2[row];
    e2il[hh][ii] = e2i_t[row];
    dil[hh][ii] = di_t[row];
  }
  if (tid < 256) {
#pragma unroll
    for (int e = 0; e < 8; ++e)
      lut[tid][e] = ((tid >> e) & 1) ? (_Float16)1.0f : (_Float16)0.0f;
  }
  {
#pragma unroll
    for (int t2 = 0; t2 < 2; ++t2) {
      int idx = t2 * 512 + tid;
      int row = idx >> 4, word = idx & 15;
      Ab[row][word] = Abits[((size_t)b * NN + i0 + row) * 16 + word];
    }
  }
  __syncthreads();

  int w = tid >> 6, l = tid & 63;
  int hh = w & 1, jq4 = w >> 1;
  int kg = l >> 4, ln = l & 15;
  v2h si_f[4], e2_f[4], di_f[4];
#pragma unroll
  for (int f = 0; f < 4; ++f) {
    _Float16 s = (_Float16)sil[hh][f * 16 + ln];
    _Float16 e = (_Float16)e2il[hh][f * 16 + ln];
    _Float16 d = (_Float16)dil[hh][f * 16 + ln];
    si_f[f][0] = s; si_f[f][1] = s;
    e2_f[f][0] = e; e2_f[f][1] = e;
    di_f[f][0] = d; di_f[f][1] = d;
  }
  v2h big = {(_Float16)4096.0f, (_Float16)4096.0f};
  int bh = b * HH + hp * 2 + hh;
  v4f acc[4][4] = {};
  const _Float16* VTb = WhTt + (size_t)bh * 32 * 64 * 32;
  int jbase = jq4 * 256;

  for (int jq = 0; jq < 8; ++jq) {
    int j = jbase + jq * 32 + kg * 8;
    int widx = j >> 6, sh = j & 63;
    U8 tj8, dj8, ej8;
    tj8.v = *(const v8h*)&tjl[hh][j];
    dj8.v = *(const v8h*)&djl[hh][j];
    ej8.v = *(const v8h*)&e2jl[hh][j];
    const _Float16* vb = VTb + (size_t)(j >> 5) * 2048 + kg * 8;
    v8h b0 = *(const v8h*)(vb + (0 * 16 + ln) * 32);
    v8h b1 = *(const v8h*)(vb + (1 * 16 + ln) * 32);
    v8h b2 = *(const v8h*)(vb + (2 * 16 + ln) * 32);
    v8h b3 = *(const v8h*)(vb + (3 * 16 + ln) * 32);
#pragma unroll
    for (int f = 0; f < 4; ++f) {
      unsigned int bits = (unsigned int)(Ab[f * 16 + ln][widx] >> sh) & 0xffu;
      U8 m, af;
      m.v = *(const v8h*)&lut[bits][0];
#pragma unroll
      for (int q = 0; q < 4; ++q) {
        v2h fv = tj8.p[q] + si_f[f];
        v2h s = clamp01(fv * big);
        v2h ej = s * dj8.p[q] + ej8.p[q];
        v2h ei = s * di_f[f] + e2_f[f];
        af.p[q] = ei * ej * m.p[q];
      }
      acc[f][0] =
          __builtin_amdgcn_mfma_f32_16x16x32_f16(af.v, b0, acc[f][0], 0, 0, 0);
      acc[f][1] =
          __builtin_amdgcn_mfma_f32_16x16x32_f16(af.v, b1, acc[f][1], 0, 0, 0);
      acc[f][2] =
          __builtin_amdgcn_mfma_f32_16x16x32_f16(af.v, b2, acc[f][2], 0, 0, 0);
      acc[f][3] =
          __builtin_amdgcn_mfma_f32_16x16x32_f16(af.v, b3, acc[f][3], 0, 0, 0);
    }
  }

#pragma unroll
  for (int pass = 0; pass < 2; ++pass) {
    int fA = pass * 2, fB = pass * 2 + 1;
    if (pass) __syncthreads();
    if (jq4 == 1 || jq4 == 3) {
      int slot = jq4 >> 1;
#pragma unroll
      for (int t = 0; t < 4; ++t)
#pragma unroll
        for (int r = 0; r < 4; ++r) {
          red[hh][slot][l][t * 4 + r] = acc[fA][t][r];
          red[hh][slot][l][16 + t * 4 + r] = acc[fB][t][r];
        }
    }
    __syncthreads();
    if (jq4 == 0 || jq4 == 2) {
      int slot = jq4 >> 1;
#pragma unroll
      for (int t = 0; t < 4; ++t)
#pragma unroll
        for (int r = 0; r < 4; ++r) {
          acc[fA][t][r] += red[hh][slot][l][t * 4 + r];
          acc[fB][t][r] += red[hh][slot][l][16 + t * 4 + r];
        }
    }
    __syncthreads();
    if (jq4 == 2) {
#pragma unroll
      for (int t = 0; t < 4; ++t)
#pragma unroll
        for (int r = 0; r < 4; ++r) {
          red[hh][0][l][t * 4 + r] = acc[fA][t][r];
          red[hh][0][l][16 + t * 4 + r] = acc[fB][t][r];
        }
    }
    __syncthreads();
    if (jq4 == 0) {
#pragma unroll
      for (int t = 0; t < 4; ++t)
#pragma unroll
        for (int r = 0; r < 4; ++r) {
          acc[fA][t][r] += red[hh][0][l][t * 4 + r];
          acc[fB][t][r] += red[hh][0][l][16 + t * 4 + r];
        }
#pragma unroll
      for (int r = 0; r < 4; ++r) {
        int giA = i0 + fA * 16 + kg * 4 + r;
        float* opA = out + ((size_t)b * NN + giA) * 256 + (hp * 2 + hh) * 64;
        opA[0 * 16 + ln] = acc[fA][0][r];
        opA[1 * 16 + ln] = acc[fA][1][r];
        opA[2 * 16 + ln] = acc[fA][2][r];
        opA[3 * 16 + ln] = acc[fA][3][r];
        float* opB = opA + 16 * 256;
        opB[0 * 16 + ln] = acc[fB][0][r];
        opB[1 * 16 + ln] = acc[fB][1][r];
        opB[2 * 16 + ln] = acc[fB][2][r];
        opB[3 * 16 + ln] = acc[fB][3][r];
      }
    }
  }
}

extern "C" void kernel_launch(void* const* d_in, const int* in_sizes, int n_in,
                              void* d_out, int out_size, void* d_ws,
                              size_t ws_size, hipStream_t stream) {
  const float* A = (const float*)d_in[0];
  const float* x = (const float*)d_in[1];
  const float* W = (const float*)d_in[2];
  const float* aw = (const float*)d_in[3];
  const float* ab = (const float*)d_in[4];
  float* out = (float*)d_out;
  char* ws = (char*)d_ws;
  _Float16* WhTt = (_Float16*)ws;                       // 4 MB tiled Wh
  _Float16* Wtt = (_Float16*)(ws + (4u << 20));         // 64 KB
  float* si2 = (float*)(ws + (4u << 20) + (64u << 10));     // 128 KB
  float* colsum = (float*)(ws + (4u << 20) + (192u << 10)); // 128 KB
  unsigned long long* Abits =
      (unsigned long long*)(ws + (4u << 20) + (320u << 10));  // 1 MB
  char* tb = ws + (5u << 20) + (320u << 10);
  _Float16* tjh = (_Float16*)tb;                   // 64 KB (B,H,N) f16
  _Float16* djh = (_Float16*)(tb + (64u << 10));   // 64 KB
  _Float16* e2jh = (_Float16*)(tb + (128u << 10)); // 64 KB
  float* e2i_t = (float*)(tb + (192u << 10));      // 128 KB
  float* di_t = (float*)(tb + (320u << 10));       // 128 KB

  hipLaunchKernelGGL(k0_wt, dim3(8), dim3(256), 0, stream, W, Wtt);
  hipLaunchKernelGGL(k1_whm, dim3(512), dim3(256), 0, stream, x, Wtt, aw, ab,
                     WhTt, si2, tjh, djh, e2jh, e2i_t, di_t, colsum);
  hipLaunchKernelGGL(kb_colsum_bits, dim3(4, 32, BB), dim3(256), 0, stream, A,
                     si2, e2i_t, di_t, tjh, djh, e2jh, colsum, Abits);
  hipLaunchKernelGGL(k4_pv, dim3(256), dim3(512), 0, stream, Abits, si2, tjh,
                     djh, e2jh, e2i_t, di_t, WhTt, colsum, out);
}